// Round 6
// baseline (217.147 us; speedup 1.0000x reference)
//
#include <hip/hip_runtime.h>
#include <hip/hip_bf16.h>

#define NB 4
#define NQ 512
#define NK 2048
#define ND 256
#define NH 64
#define QT 8                      // queries per attn block
#define KSPLIT 4

#define SCALE_C 2.8853900817779268f   // 2*log2(e): exp2(C*(q+k)) = e^{2(q+k)}
#define L2E     1.4426950408889634f

__device__ __forceinline__ float wred_sum(float v) {
#pragma unroll
    for (int off = 32; off; off >>= 1) v += __shfl_xor(v, off, 64);
    return v;
}

// ---------- kernel A: projections, pre-scaled by 2*log2(e) ----------
// queries -> qp[b*NQ+q][h] (row-major); keys -> kpT[b][h][k] (TRANSPOSED)
__global__ __launch_bounds__(256) void proj_kernel(
    const float* __restrict__ queries, const float* __restrict__ keys,
    const float* __restrict__ Wq, const float* __restrict__ Wk,
    float* __restrict__ qp, float* __restrict__ kpT)
{
    __shared__ __align__(16) float in_lds[16][256];
    const int t = threadIdx.x;
    const int row0 = blockIdx.x * 16;
    const bool isQ = row0 < NB * NQ;
    const float* src = isQ ? (queries + (size_t)row0 * ND)
                           : (keys + (size_t)(row0 - NB * NQ) * ND);
    const float* W = isQ ? Wq : Wk;

    const float4* src4 = (const float4*)src;
#pragma unroll
    for (int i = 0; i < 4; ++i) {
        int f4 = t + 256 * i;
        ((float4*)&in_lds[0][0])[f4] = src4[f4];
    }
    __syncthreads();

    const int w = t >> 6, h = t & 63;
    const int r0 = w * 4;
    float a[4] = {0.f, 0.f, 0.f, 0.f};
#pragma unroll 4
    for (int d4 = 0; d4 < 64; ++d4) {
        const float* Wp = W + (size_t)(d4 * 4) * NH + h;
        float w0 = Wp[0], w1 = Wp[NH], w2 = Wp[2 * NH], w3 = Wp[3 * NH];
#pragma unroll
        for (int i = 0; i < 4; ++i) {
            float4 x = ((const float4*)in_lds[r0 + i])[d4];
            a[i] = fmaf(x.x, w0, fmaf(x.y, w1, fmaf(x.z, w2, fmaf(x.w, w3, a[i]))));
        }
    }
    if (isQ) {
#pragma unroll
        for (int i = 0; i < 4; ++i)
            qp[(size_t)(row0 + r0 + i) * NH + h] = a[i] * SCALE_C;
    } else {
#pragma unroll
        for (int i = 0; i < 4; ++i) {
            int kr = row0 - NB * NQ + r0 + i;         // global key row
            int b = kr >> 11, k = kr & (NK - 1);
            kpT[((size_t)((b << 6) + h)) * NK + k] = a[i] * SCALE_C;  // scattered, tiny
        }
    }
}

// ---------- kernel B: partial scores + no-max softmax + partial PV ----------
// grid = NB*(NQ/QT)*KSPLIT = 1024 blocks, 512 threads (8 waves), all resident.
// Block decode (diagonal batch<->split pairing):
//   g = n & 255, s = n >> 8, b = ((g>>6)+s)&3, qt = g&63.
// DYNAMIC split of the VALID key range: block covers k in [bnd(s), bnd(s+1)),
// bnd(i) = (kveff*i/4) & ~7 -> every split has ~kveff/4 keys -> per-CU work is
// (sum_b kv_b)/4 regardless of the valid_lens draw.
__global__ __launch_bounds__(512, 8) void attn_part(
    const float* __restrict__ values, const int* __restrict__ valid_lens,
    const float* __restrict__ wv,
    const float* __restrict__ qp, const float* __restrict__ kpT,
    float* __restrict__ po, float* __restrict__ pml)
{
    __shared__ __align__(16) float wv2_l[NH];         // -2*wv
    __shared__ float sumwv_l;
    __shared__ __align__(16) float buf[8192];         // 32 KB: p (k-major) / red scratch
    __shared__ float red_l[QT][8];

    const int t = threadIdx.x;
    const int n = blockIdx.x;
    const int g = n & 255;
    const int sp = n >> 8;
    const int b  = ((g >> 6) + sp) & 3;
    const int qt = g & 63;
    const int q0 = qt * QT;
    const int wid = t >> 6;
    const int dl = (t & 63) * 4;

    if (t < 64) {
        float wvv = wv[t];
        wv2_l[t] = -2.0f * wvv;
        float s = wred_sum(wvv);
        if (t == 0) sumwv_l = s;
    }
    int vl = valid_lens[b];
    const int kv = vl < 0 ? 0 : (vl > NK ? NK : vl);
    const int kveff = (kv == 0) ? NK : kv;    // kv==0 -> uniform over all keys
    // dynamic split bounds (multiples of 8)
    const int kstart = (kveff * sp / 4) & ~7;
    const int kend   = (sp == 3) ? ((kveff + 7) & ~7) : ((kveff * (sp + 1) / 4) & ~7);
    const int range8 = kend - kstart;         // <= 520, multiple of 8
    __syncthreads();
    const float sumwv = sumwv_l;

    const float* qpg = qp + (size_t)(b * NQ + q0) * NH;   // block-uniform base

    // ---- phase 1: e-values into buf (k-major [range8][8]) ----
    float sum_q[QT];
#pragma unroll
    for (int q = 0; q < QT; ++q) sum_q[q] = 0.f;

    for (int kl = t; kl < range8; kl += 512) {
        const int kg = kstart + kl;           // < 2048 always (kend <= 2048)
        float s[QT];
#pragma unroll
        for (int q = 0; q < QT; ++q) s[q] = sumwv;
        const float* kT = kpT + ((size_t)(b << 6)) * NK + kg;   // coalesced, h-stride NK
#pragma unroll
        for (int hb = 0; hb < 8; ++hb) {
            float kh[8];
#pragma unroll
            for (int i = 0; i < 8; ++i) kh[i] = kT[(size_t)(hb * 8 + i) * NK];
#pragma unroll
            for (int hq = 0; hq < 2; ++hq) {
                const int h4 = hb * 2 + hq;
                float4 w4 = ((const float4*)wv2_l)[h4];
                float k0 = kh[hq * 4], k1 = kh[hq * 4 + 1],
                      k2 = kh[hq * 4 + 2], k3 = kh[hq * 4 + 3];
#pragma unroll
                for (int q = 0; q < QT; ++q) {
                    // block-uniform address -> scalar load (SGPR operands)
                    float4 qh = *(const float4*)(qpg + q * NH + h4 * 4);
                    float r0 = __builtin_amdgcn_rcpf(__builtin_amdgcn_exp2f(qh.x + k0) + 1.0f);
                    float r1 = __builtin_amdgcn_rcpf(__builtin_amdgcn_exp2f(qh.y + k1) + 1.0f);
                    float r2 = __builtin_amdgcn_rcpf(__builtin_amdgcn_exp2f(qh.z + k2) + 1.0f);
                    float r3 = __builtin_amdgcn_rcpf(__builtin_amdgcn_exp2f(qh.w + k3) + 1.0f);
                    s[q] = fmaf(w4.x, r0, s[q]);
                    s[q] = fmaf(w4.y, r1, s[q]);
                    s[q] = fmaf(w4.z, r2, s[q]);
                    s[q] = fmaf(w4.w, r3, s[q]);
                }
            }
        }
        const bool valid = kg < kv;           // branchless mask (kv==0 -> always false -> 1.0)
        const float fill = (kv == 0) ? 1.0f : 0.0f;
        float e[QT];
#pragma unroll
        for (int q = 0; q < QT; ++q) {
            float ev = __builtin_amdgcn_exp2f(s[q] * L2E);
            e[q] = valid ? ev : fill;
            sum_q[q] += e[q];
        }
        *(float4*)&buf[kl * 8]     = make_float4(e[0], e[1], e[2], e[3]);
        *(float4*)&buf[kl * 8 + 4] = make_float4(e[4], e[5], e[6], e[7]);
    }
#pragma unroll
    for (int q = 0; q < QT; ++q) {
        float s = wred_sum(sum_q[q]);
        if ((t & 63) == 0) red_l[q][wid] = s;
    }
    __syncthreads();

    // ---- phase 2: PV, waves split k (row kl handled by wave kl%8) ----
    float4 acc[QT];
#pragma unroll
    for (int q = 0; q < QT; ++q) acc[q] = make_float4(0.f, 0.f, 0.f, 0.f);

    const float* Vb = values + ((size_t)b * NK + kstart) * ND;
#pragma unroll 2
    for (int kl = wid; kl < range8; kl += 8) {
        float4 pA = *(const float4*)&buf[kl * 8];       // wave-uniform broadcast
        float4 pB = *(const float4*)&buf[kl * 8 + 4];
        float4 v = *(const float4*)(Vb + (size_t)kl * ND + dl);  // coalesced 1KB
        acc[0].x = fmaf(pA.x, v.x, acc[0].x); acc[0].y = fmaf(pA.x, v.y, acc[0].y);
        acc[0].z = fmaf(pA.x, v.z, acc[0].z); acc[0].w = fmaf(pA.x, v.w, acc[0].w);
        acc[1].x = fmaf(pA.y, v.x, acc[1].x); acc[1].y = fmaf(pA.y, v.y, acc[1].y);
        acc[1].z = fmaf(pA.y, v.z, acc[1].z); acc[1].w = fmaf(pA.y, v.w, acc[1].w);
        acc[2].x = fmaf(pA.z, v.x, acc[2].x); acc[2].y = fmaf(pA.z, v.y, acc[2].y);
        acc[2].z = fmaf(pA.z, v.z, acc[2].z); acc[2].w = fmaf(pA.z, v.w, acc[2].w);
        acc[3].x = fmaf(pA.w, v.x, acc[3].x); acc[3].y = fmaf(pA.w, v.y, acc[3].y);
        acc[3].z = fmaf(pA.w, v.z, acc[3].z); acc[3].w = fmaf(pA.w, v.w, acc[3].w);
        acc[4].x = fmaf(pB.x, v.x, acc[4].x); acc[4].y = fmaf(pB.x, v.y, acc[4].y);
        acc[4].z = fmaf(pB.x, v.z, acc[4].z); acc[4].w = fmaf(pB.x, v.w, acc[4].w);
        acc[5].x = fmaf(pB.y, v.x, acc[5].x); acc[5].y = fmaf(pB.y, v.y, acc[5].y);
        acc[5].z = fmaf(pB.y, v.z, acc[5].z); acc[5].w = fmaf(pB.y, v.w, acc[5].w);
        acc[6].x = fmaf(pB.z, v.x, acc[6].x); acc[6].y = fmaf(pB.z, v.y, acc[6].y);
        acc[6].z = fmaf(pB.z, v.z, acc[6].z); acc[6].w = fmaf(pB.z, v.w, acc[6].w);
        acc[7].x = fmaf(pB.w, v.x, acc[7].x); acc[7].y = fmaf(pB.w, v.y, acc[7].y);
        acc[7].z = fmaf(pB.w, v.z, acc[7].z); acc[7].w = fmaf(pB.w, v.w, acc[7].w);
    }
    __syncthreads();                          // p-values dead -> reuse buf as scratch

    // ---- phase 3: tree-reduce partials across waves (8 -> 4 -> 2 -> 1) ----
    if (wid >= 4) {
        float* s = buf + (size_t)(wid - 4) * 2048;
#pragma unroll
        for (int q = 0; q < QT; ++q) *(float4*)(s + q * 256 + dl) = acc[q];
    }
    __syncthreads();
    if (wid < 4) {
        const float* s = buf + (size_t)wid * 2048;
#pragma unroll
        for (int q = 0; q < QT; ++q) {
            float4 r = *(const float4*)(s + q * 256 + dl);
            acc[q].x += r.x; acc[q].y += r.y; acc[q].z += r.z; acc[q].w += r.w;
        }
    }
    __syncthreads();
    if (wid >= 2 && wid < 4) {
        float* s = buf + (size_t)(wid - 2) * 2048;
#pragma unroll
        for (int q = 0; q < QT; ++q) *(float4*)(s + q * 256 + dl) = acc[q];
    }
    __syncthreads();
    if (wid < 2) {
        const float* s = buf + (size_t)wid * 2048;
#pragma unroll
        for (int q = 0; q < QT; ++q) {
            float4 r = *(const float4*)(s + q * 256 + dl);
            acc[q].x += r.x; acc[q].y += r.y; acc[q].z += r.z; acc[q].w += r.w;
        }
    }
    __syncthreads();
    if (wid == 1) {
#pragma unroll
        for (int q = 0; q < QT; ++q) *(float4*)(buf + q * 256 + dl) = acc[q];
    }
    __syncthreads();
    if (wid == 0) {
#pragma unroll
        for (int q = 0; q < QT; ++q) {
            float4 r = *(const float4*)(buf + q * 256 + dl);
            acc[q].x += r.x; acc[q].y += r.y; acc[q].z += r.z; acc[q].w += r.w;
            const size_t row4 = ((size_t)(b * NQ + q0 + q) * KSPLIT + sp);
            *(float4*)(po + row4 * ND + dl) = acc[q];
        }
        if (t < QT) {
            float l = 0.f;
#pragma unroll
            for (int i = 0; i < 8; ++i) l += red_l[t][i];
            pml[((size_t)(b * NQ + q0 + t) * KSPLIT + sp)] = l;
        }
    }
}

// ---------- kernel C: combine the four splits ----------
__global__ __launch_bounds__(256) void combine_kernel(
    const float* __restrict__ po, const float* __restrict__ pml,
    float* __restrict__ out)
{
    const int t = threadIdx.x;
    const int row = blockIdx.x * 4 + (t >> 6);
    const int dl = (t & 63) * 4;
    float l = 0.f;
#pragma unroll
    for (int s = 0; s < KSPLIT; ++s) l += pml[row * KSPLIT + s];
    float4 o = make_float4(0.f, 0.f, 0.f, 0.f);
#pragma unroll
    for (int s = 0; s < KSPLIT; ++s) {
        float4 p = *(const float4*)(po + ((size_t)row * KSPLIT + s) * ND + dl);
        o.x += p.x; o.y += p.y; o.z += p.z; o.w += p.w;
    }
    const float inv = 1.0f / l;
    o.x *= inv; o.y *= inv; o.z *= inv; o.w *= inv;
    *(float4*)(out + (size_t)row * ND + dl) = o;
}

extern "C" void kernel_launch(void* const* d_in, const int* in_sizes, int n_in,
                              void* d_out, int out_size, void* d_ws, size_t ws_size,
                              hipStream_t stream) {
    const float* queries   = (const float*)d_in[0];
    const float* keys      = (const float*)d_in[1];
    const float* values    = (const float*)d_in[2];
    const int* valid_lens  = (const int*)d_in[3];
    const float* Wq        = (const float*)d_in[4];
    const float* Wk        = (const float*)d_in[5];
    const float* wv        = (const float*)d_in[6];
    float* out = (float*)d_out;

    float* qp  = (float*)d_ws;                          // NB*NQ*NH      (0.5 MB)
    float* kpT = qp + (size_t)NB * NQ * NH;             // NB*NH*NK      (2 MB)
    float* po  = kpT + (size_t)NB * NH * NK;            // NB*NQ*4*ND    (8 MB)
    float* pml = po + (size_t)NB * NQ * KSPLIT * ND;    // NB*NQ*4

    proj_kernel<<<(NB * NQ + NB * NK) / 16, 256, 0, stream>>>(queries, keys, Wq, Wk, qp, kpT);
    attn_part<<<NB * (NQ / QT) * KSPLIT, 512, 0, stream>>>(values, valid_lens, wv, qp, kpT, po, pml);
    combine_kernel<<<NB * NQ / 4, 256, 0, stream>>>(po, pml, out);
}

// Round 7
// 191.693 us; speedup vs baseline: 1.1328x; 1.1328x over previous
//
#include <hip/hip_runtime.h>
#include <hip/hip_bf16.h>

#define NB 4
#define NQ 512
#define NK 2048
#define ND 256
#define NH 64
#define QT 8                      // queries per attn block
#define KSPLIT 4

#define SCALE_C 2.8853900817779268f   // 2*log2(e): exp2(C*(q+k)) = e^{2(q+k)}
#define L2E     1.4426950408889634f

__device__ __forceinline__ float wred_sum(float v) {
#pragma unroll
    for (int off = 32; off; off >>= 1) v += __shfl_xor(v, off, 64);
    return v;
}

// ---------- kernel A: projections, pre-scaled by 2*log2(e) ----------
// queries -> qp[b*NQ+q][h] (row-major); keys -> kpT[b][h][k] (TRANSPOSED)
__global__ __launch_bounds__(256) void proj_kernel(
    const float* __restrict__ queries, const float* __restrict__ keys,
    const float* __restrict__ Wq, const float* __restrict__ Wk,
    float* __restrict__ qp, float* __restrict__ kpT)
{
    __shared__ __align__(16) float in_lds[16][256];
    const int t = threadIdx.x;
    const int row0 = blockIdx.x * 16;
    const bool isQ = row0 < NB * NQ;
    const float* src = isQ ? (queries + (size_t)row0 * ND)
                           : (keys + (size_t)(row0 - NB * NQ) * ND);
    const float* W = isQ ? Wq : Wk;

    const float4* src4 = (const float4*)src;
#pragma unroll
    for (int i = 0; i < 4; ++i) {
        int f4 = t + 256 * i;
        ((float4*)&in_lds[0][0])[f4] = src4[f4];
    }
    __syncthreads();

    const int w = t >> 6, h = t & 63;
    const int r0 = w * 4;
    float a[4] = {0.f, 0.f, 0.f, 0.f};
#pragma unroll 4
    for (int d4 = 0; d4 < 64; ++d4) {
        const float* Wp = W + (size_t)(d4 * 4) * NH + h;
        float w0 = Wp[0], w1 = Wp[NH], w2 = Wp[2 * NH], w3 = Wp[3 * NH];
#pragma unroll
        for (int i = 0; i < 4; ++i) {
            float4 x = ((const float4*)in_lds[r0 + i])[d4];
            a[i] = fmaf(x.x, w0, fmaf(x.y, w1, fmaf(x.z, w2, fmaf(x.w, w3, a[i]))));
        }
    }
    if (isQ) {
#pragma unroll
        for (int i = 0; i < 4; ++i)
            qp[(size_t)(row0 + r0 + i) * NH + h] = a[i] * SCALE_C;
    } else {
#pragma unroll
        for (int i = 0; i < 4; ++i) {
            int kr = row0 - NB * NQ + r0 + i;         // global key row
            int b = kr >> 11, k = kr & (NK - 1);
            kpT[((size_t)((b << 6) + h)) * NK + k] = a[i] * SCALE_C;  // scattered, tiny
        }
    }
}

// ---------- kernel B: partial scores + no-max softmax + partial PV ----------
// grid = NB*(NQ/QT)*KSPLIT = 1024 blocks, 512 threads (8 waves), all resident.
// Block decode (diagonal batch<->split pairing): g = n&255, sp = n>>8,
//   b = ((g>>6)+sp)&3, qt = g&63.
// DYNAMIC split of the VALID key range: block covers k in [bnd(sp), bnd(sp+1)),
// bnd(i) = (kveff*i/4) & ~7 -> every split ~kveff/4 keys -> per-CU work is
// (sum_b kv_b)/4 regardless of the valid_lens draw.
__global__ __launch_bounds__(512, 8) void attn_part(
    const float* __restrict__ values, const int* __restrict__ valid_lens,
    const float* __restrict__ wv,
    const float* __restrict__ qp, const float* __restrict__ kpT,
    float* __restrict__ po, float* __restrict__ pml)
{
    __shared__ __align__(16) float qp_l[QT][NH];      // 2 KB (LDS broadcast source)
    __shared__ __align__(16) float wv2_l[NH];         // -2*wv
    __shared__ float sumwv_l;
    __shared__ __align__(16) float buf[8192];         // 32 KB: p (k-major) / red scratch
    __shared__ float red_l[QT][8];

    const int t = threadIdx.x;
    const int n = blockIdx.x;
    const int g = n & 255;
    const int sp = n >> 8;
    const int b  = ((g >> 6) + sp) & 3;
    const int qt = g & 63;
    const int q0 = qt * QT;
    const int wid = t >> 6;
    const int dl = (t & 63) * 4;

    if (t < 128) {
        int q = t >> 4, h4 = t & 15;
        ((float4*)qp_l[q])[h4] =
            ((const float4*)(qp + (size_t)(b * NQ + q0 + q) * NH))[h4];
    }
    if (t < 64) {
        float wvv = wv[t];
        wv2_l[t] = -2.0f * wvv;
        float s = wred_sum(wvv);
        if (t == 0) sumwv_l = s;
    }
    int vl = valid_lens[b];
    const int kv = vl < 0 ? 0 : (vl > NK ? NK : vl);
    const int kveff = (kv == 0) ? NK : kv;    // kv==0 -> uniform over all keys
    // dynamic split bounds (multiples of 8)
    const int kstart = (kveff * sp / 4) & ~7;
    const int kend   = (sp == 3) ? ((kveff + 7) & ~7) : ((kveff * (sp + 1) / 4) & ~7);
    const int range8 = kend - kstart;         // <= 520, multiple of 8
    __syncthreads();
    const float sumwv = sumwv_l;

    // ---- phase 1: e-values into buf (k-major [range8][8]) ----
    float sum_q[QT];
#pragma unroll
    for (int q = 0; q < QT; ++q) sum_q[q] = 0.f;

    for (int kl = t; kl < range8; kl += 512) {
        const int kg = kstart + kl;           // < 2048 always
        float e[QT];
        if (kv == 0) {
#pragma unroll
            for (int q = 0; q < QT; ++q) e[q] = 1.0f;
        } else if (kg < kv) {
            float s[QT];
#pragma unroll
            for (int q = 0; q < QT; ++q) s[q] = sumwv;
            const float* kT = kpT + ((size_t)(b << 6)) * NK + kg;   // coalesced, h-stride NK
#pragma unroll
            for (int hb = 0; hb < 8; ++hb) {
                float kh[8];
#pragma unroll
                for (int i = 0; i < 8; ++i) kh[i] = kT[(size_t)(hb * 8 + i) * NK];
#pragma unroll
                for (int hq = 0; hq < 2; ++hq) {
                    const int h4 = hb * 2 + hq;
                    float4 w4 = ((const float4*)wv2_l)[h4];
                    float k0 = kh[hq * 4], k1 = kh[hq * 4 + 1],
                          k2 = kh[hq * 4 + 2], k3 = kh[hq * 4 + 3];
#pragma unroll
                    for (int q = 0; q < QT; ++q) {
                        float4 qh = ((const float4*)qp_l[q])[h4];   // LDS broadcast
                        float r0 = __builtin_amdgcn_rcpf(__builtin_amdgcn_exp2f(qh.x + k0) + 1.0f);
                        float r1 = __builtin_amdgcn_rcpf(__builtin_amdgcn_exp2f(qh.y + k1) + 1.0f);
                        float r2 = __builtin_amdgcn_rcpf(__builtin_amdgcn_exp2f(qh.z + k2) + 1.0f);
                        float r3 = __builtin_amdgcn_rcpf(__builtin_amdgcn_exp2f(qh.w + k3) + 1.0f);
                        s[q] = fmaf(w4.x, r0, s[q]);
                        s[q] = fmaf(w4.y, r1, s[q]);
                        s[q] = fmaf(w4.z, r2, s[q]);
                        s[q] = fmaf(w4.w, r3, s[q]);
                    }
                }
            }
#pragma unroll
            for (int q = 0; q < QT; ++q) e[q] = __builtin_amdgcn_exp2f(s[q] * L2E);
        } else {
#pragma unroll
            for (int q = 0; q < QT; ++q) e[q] = 0.f;
        }
        *(float4*)&buf[kl * 8]     = make_float4(e[0], e[1], e[2], e[3]);
        *(float4*)&buf[kl * 8 + 4] = make_float4(e[4], e[5], e[6], e[7]);
#pragma unroll
        for (int q = 0; q < QT; ++q) sum_q[q] += e[q];
    }
#pragma unroll
    for (int q = 0; q < QT; ++q) {
        float s = wred_sum(sum_q[q]);
        if ((t & 63) == 0) red_l[q][wid] = s;
    }
    __syncthreads();

    // ---- phase 2: PV, waves split k (row kl handled by wave kl%8) ----
    float4 acc[QT];
#pragma unroll
    for (int q = 0; q < QT; ++q) acc[q] = make_float4(0.f, 0.f, 0.f, 0.f);

    const float* Vb = values + ((size_t)b * NK + kstart) * ND;
#pragma unroll 2
    for (int kl = wid; kl < range8; kl += 8) {
        float4 pA = *(const float4*)&buf[kl * 8];       // wave-uniform broadcast
        float4 pB = *(const float4*)&buf[kl * 8 + 4];
        float4 v = *(const float4*)(Vb + (size_t)kl * ND + dl);  // coalesced 1KB
        acc[0].x = fmaf(pA.x, v.x, acc[0].x); acc[0].y = fmaf(pA.x, v.y, acc[0].y);
        acc[0].z = fmaf(pA.x, v.z, acc[0].z); acc[0].w = fmaf(pA.x, v.w, acc[0].w);
        acc[1].x = fmaf(pA.y, v.x, acc[1].x); acc[1].y = fmaf(pA.y, v.y, acc[1].y);
        acc[1].z = fmaf(pA.y, v.z, acc[1].z); acc[1].w = fmaf(pA.y, v.w, acc[1].w);
        acc[2].x = fmaf(pA.z, v.x, acc[2].x); acc[2].y = fmaf(pA.z, v.y, acc[2].y);
        acc[2].z = fmaf(pA.z, v.z, acc[2].z); acc[2].w = fmaf(pA.z, v.w, acc[2].w);
        acc[3].x = fmaf(pA.w, v.x, acc[3].x); acc[3].y = fmaf(pA.w, v.y, acc[3].y);
        acc[3].z = fmaf(pA.w, v.z, acc[3].z); acc[3].w = fmaf(pA.w, v.w, acc[3].w);
        acc[4].x = fmaf(pB.x, v.x, acc[4].x); acc[4].y = fmaf(pB.x, v.y, acc[4].y);
        acc[4].z = fmaf(pB.x, v.z, acc[4].z); acc[4].w = fmaf(pB.x, v.w, acc[4].w);
        acc[5].x = fmaf(pB.y, v.x, acc[5].x); acc[5].y = fmaf(pB.y, v.y, acc[5].y);
        acc[5].z = fmaf(pB.y, v.z, acc[5].z); acc[5].w = fmaf(pB.y, v.w, acc[5].w);
        acc[6].x = fmaf(pB.z, v.x, acc[6].x); acc[6].y = fmaf(pB.z, v.y, acc[6].y);
        acc[6].z = fmaf(pB.z, v.z, acc[6].z); acc[6].w = fmaf(pB.z, v.w, acc[6].w);
        acc[7].x = fmaf(pB.w, v.x, acc[7].x); acc[7].y = fmaf(pB.w, v.y, acc[7].y);
        acc[7].z = fmaf(pB.w, v.z, acc[7].z); acc[7].w = fmaf(pB.w, v.w, acc[7].w);
    }
    __syncthreads();                          // p-values dead -> reuse buf as scratch

    // ---- phase 3: tree-reduce partials across waves (8 -> 4 -> 2 -> 1) ----
    if (wid >= 4) {
        float* s = buf + (size_t)(wid - 4) * 2048;
#pragma unroll
        for (int q = 0; q < QT; ++q) *(float4*)(s + q * 256 + dl) = acc[q];
    }
    __syncthreads();
    if (wid < 4) {
        const float* s = buf + (size_t)wid * 2048;
#pragma unroll
        for (int q = 0; q < QT; ++q) {
            float4 r = *(const float4*)(s + q * 256 + dl);
            acc[q].x += r.x; acc[q].y += r.y; acc[q].z += r.z; acc[q].w += r.w;
        }
    }
    __syncthreads();
    if (wid >= 2 && wid < 4) {
        float* s = buf + (size_t)(wid - 2) * 2048;
#pragma unroll
        for (int q = 0; q < QT; ++q) *(float4*)(s + q * 256 + dl) = acc[q];
    }
    __syncthreads();
    if (wid < 2) {
        const float* s = buf + (size_t)wid * 2048;
#pragma unroll
        for (int q = 0; q < QT; ++q) {
            float4 r = *(const float4*)(s + q * 256 + dl);
            acc[q].x += r.x; acc[q].y += r.y; acc[q].z += r.z; acc[q].w += r.w;
        }
    }
    __syncthreads();
    if (wid == 1) {
#pragma unroll
        for (int q = 0; q < QT; ++q) *(float4*)(buf + q * 256 + dl) = acc[q];
    }
    __syncthreads();
    if (wid == 0) {
#pragma unroll
        for (int q = 0; q < QT; ++q) {
            float4 r = *(const float4*)(buf + q * 256 + dl);
            acc[q].x += r.x; acc[q].y += r.y; acc[q].z += r.z; acc[q].w += r.w;
            const size_t row4 = ((size_t)(b * NQ + q0 + q) * KSPLIT + sp);
            *(float4*)(po + row4 * ND + dl) = acc[q];
        }
        if (t < QT) {
            float l = 0.f;
#pragma unroll
            for (int i = 0; i < 8; ++i) l += red_l[t][i];
            pml[((size_t)(b * NQ + q0 + t) * KSPLIT + sp)] = l;
        }
    }
}

// ---------- kernel C: combine the four splits ----------
__global__ __launch_bounds__(256) void combine_kernel(
    const float* __restrict__ po, const float* __restrict__ pml,
    float* __restrict__ out)
{
    const int t = threadIdx.x;
    const int row = blockIdx.x * 4 + (t >> 6);
    const int dl = (t & 63) * 4;
    float l = 0.f;
#pragma unroll
    for (int s = 0; s < KSPLIT; ++s) l += pml[row * KSPLIT + s];
    float4 o = make_float4(0.f, 0.f, 0.f, 0.f);
#pragma unroll
    for (int s = 0; s < KSPLIT; ++s) {
        float4 p = *(const float4*)(po + ((size_t)row * KSPLIT + s) * ND + dl);
        o.x += p.x; o.y += p.y; o.z += p.z; o.w += p.w;
    }
    const float inv = 1.0f / l;
    o.x *= inv; o.y *= inv; o.z *= inv; o.w *= inv;
    *(float4*)(out + (size_t)row * ND + dl) = o;
}

extern "C" void kernel_launch(void* const* d_in, const int* in_sizes, int n_in,
                              void* d_out, int out_size, void* d_ws, size_t ws_size,
                              hipStream_t stream) {
    const float* queries   = (const float*)d_in[0];
    const float* keys      = (const float*)d_in[1];
    const float* values    = (const float*)d_in[2];
    const int* valid_lens  = (const int*)d_in[3];
    const float* Wq        = (const float*)d_in[4];
    const float* Wk        = (const float*)d_in[5];
    const float* wv        = (const float*)d_in[6];
    float* out = (float*)d_out;

    float* qp  = (float*)d_ws;                          // NB*NQ*NH      (0.5 MB)
    float* kpT = qp + (size_t)NB * NQ * NH;             // NB*NH*NK      (2 MB)
    float* po  = kpT + (size_t)NB * NH * NK;            // NB*NQ*4*ND    (8 MB)
    float* pml = po + (size_t)NB * NQ * KSPLIT * ND;    // NB*NQ*4

    proj_kernel<<<(NB * NQ + NB * NK) / 16, 256, 0, stream>>>(queries, keys, Wq, Wk, qp, kpT);
    attn_part<<<NB * (NQ / QT) * KSPLIT, 512, 0, stream>>>(values, valid_lens, wv, qp, kpT, po, pml);
    combine_kernel<<<NB * NQ / 4, 256, 0, stream>>>(po, pml, out);
}

// Round 8
// 74.022 us; speedup vs baseline: 2.9336x; 2.5897x over previous
//
#include <hip/hip_runtime.h>
#include <hip/hip_bf16.h>

#define NB 4
#define NQ 512
#define NK 2048
#define ND 256
#define NH 64
#define QT 8                      // queries per attn block
#define KSPLIT 4

#define SCALE_C 2.8853900817779268f   // 2*log2(e): exp2(C*(q+k)) = e^{2(q+k)}
#define L2E     1.4426950408889634f

__device__ __forceinline__ float wred_sum(float v) {
#pragma unroll
    for (int off = 32; off; off >>= 1) v += __shfl_xor(v, off, 64);
    return v;
}

// ---------- kernel A: projections, pre-scaled by 2*log2(e) ----------
// queries -> qp[b*NQ+q][h] (row-major); keys -> kpT[b][h][k] (TRANSPOSED)
__global__ __launch_bounds__(256) void proj_kernel(
    const float* __restrict__ queries, const float* __restrict__ keys,
    const float* __restrict__ Wq, const float* __restrict__ Wk,
    float* __restrict__ qp, float* __restrict__ kpT)
{
    __shared__ __align__(16) float in_lds[16][256];
    const int t = threadIdx.x;
    const int row0 = blockIdx.x * 16;
    const bool isQ = row0 < NB * NQ;
    const float* src = isQ ? (queries + (size_t)row0 * ND)
                           : (keys + (size_t)(row0 - NB * NQ) * ND);
    const float* W = isQ ? Wq : Wk;

    const float4* src4 = (const float4*)src;
#pragma unroll
    for (int i = 0; i < 4; ++i) {
        int f4 = t + 256 * i;
        ((float4*)&in_lds[0][0])[f4] = src4[f4];
    }
    __syncthreads();

    const int w = t >> 6, h = t & 63;
    const int r0 = w * 4;
    float a[4] = {0.f, 0.f, 0.f, 0.f};
#pragma unroll 4
    for (int d4 = 0; d4 < 64; ++d4) {
        const float* Wp = W + (size_t)(d4 * 4) * NH + h;
        float w0 = Wp[0], w1 = Wp[NH], w2 = Wp[2 * NH], w3 = Wp[3 * NH];
#pragma unroll
        for (int i = 0; i < 4; ++i) {
            float4 x = ((const float4*)in_lds[r0 + i])[d4];
            a[i] = fmaf(x.x, w0, fmaf(x.y, w1, fmaf(x.z, w2, fmaf(x.w, w3, a[i]))));
        }
    }
    if (isQ) {
#pragma unroll
        for (int i = 0; i < 4; ++i)
            qp[(size_t)(row0 + r0 + i) * NH + h] = a[i] * SCALE_C;
    } else {
#pragma unroll
        for (int i = 0; i < 4; ++i) {
            int kr = row0 - NB * NQ + r0 + i;         // global key row
            int b = kr >> 11, k = kr & (NK - 1);
            kpT[((size_t)((b << 6) + h)) * NK + k] = a[i] * SCALE_C;  // scattered, tiny
        }
    }
}

// ---------- kernel B: partial scores + no-max softmax + partial PV ----------
// grid = NB*(NQ/QT)*KSPLIT = 1024 blocks, 512 threads (8 waves).
// Block decode (diagonal batch<->split pairing): g = n&255, sp = n>>8,
//   b = ((g>>6)+sp)&3, qt = g&63.
// BALANCED dynamic split with ranges GUARANTEED <= 512 (so phase 1 is a
// straight-line one-k-per-thread pass -- no dynamic-trip loop, no spill):
//   step = ceil(kveff/4) rounded up to 8; [sp*step, min(sp*step+step, kveff~8))
__global__ __launch_bounds__(512, 8) void attn_part(
    const float* __restrict__ values, const int* __restrict__ valid_lens,
    const float* __restrict__ wv,
    const float* __restrict__ qp, const float* __restrict__ kpT,
    float* __restrict__ po, float* __restrict__ pml)
{
    __shared__ __align__(16) float qp_l[QT][NH];      // 2 KB (LDS broadcast source)
    __shared__ __align__(16) float wv2_l[NH];         // -2*wv
    __shared__ float sumwv_l;
    __shared__ __align__(16) float buf[8192];         // 32 KB: p (k-major) / red scratch
    __shared__ float red_l[QT][8];

    const int t = threadIdx.x;
    const int n = blockIdx.x;
    const int g = n & 255;
    const int sp = n >> 8;
    const int b  = ((g >> 6) + sp) & 3;
    const int qt = g & 63;
    const int q0 = qt * QT;
    const int wid = t >> 6;
    const int dl = (t & 63) * 4;

    if (t < 128) {
        int q = t >> 4, h4 = t & 15;
        ((float4*)qp_l[q])[h4] =
            ((const float4*)(qp + (size_t)(b * NQ + q0 + q) * NH))[h4];
    }
    if (t < 64) {
        float wvv = wv[t];
        wv2_l[t] = -2.0f * wvv;
        float s = wred_sum(wvv);
        if (t == 0) sumwv_l = s;
    }
    int vl = valid_lens[b];
    const int kv = vl < 0 ? 0 : (vl > NK ? NK : vl);
    const int kveff = (kv == 0) ? NK : kv;    // kv==0 -> uniform over all keys
    // balanced bounds, range always multiple of 8 and <= 512
    const int step   = ((kveff + 31) & ~31) >> 2;        // ceil(kveff/4) to mult-of-8
    const int kvr8   = (kveff + 7) & ~7;
    const int kstart = sp * step;
    int kend = kstart + step; if (kend > kvr8) kend = kvr8;
    const int range8 = (kend > kstart) ? (kend - kstart) : 0;   // <= 512
    __syncthreads();
    const float sumwv = sumwv_l;

    // ---- phase 1: e-values into buf (k-major [range8][8]), ONE k per thread ----
    {
        const int kl = t;
        if (kl < range8) {
            const int kg = kstart + kl;
            float e[QT];
            if (kv == 0) {
#pragma unroll
                for (int q = 0; q < QT; ++q) e[q] = 1.0f;
            } else if (kg < kv) {
                float s[QT];
#pragma unroll
                for (int q = 0; q < QT; ++q) s[q] = sumwv;
                const float* kT = kpT + ((size_t)(b << 6)) * NK + kg;  // coalesced
#pragma unroll
                for (int hb = 0; hb < 8; ++hb) {
                    float kh[8];
#pragma unroll
                    for (int i = 0; i < 8; ++i) kh[i] = kT[(size_t)(hb * 8 + i) * NK];
#pragma unroll
                    for (int hq = 0; hq < 2; ++hq) {
                        const int h4 = hb * 2 + hq;
                        float4 w4 = ((const float4*)wv2_l)[h4];
                        float k0 = kh[hq * 4], k1 = kh[hq * 4 + 1],
                              k2 = kh[hq * 4 + 2], k3 = kh[hq * 4 + 3];
#pragma unroll
                        for (int q = 0; q < QT; ++q) {
                            float4 qh = ((const float4*)qp_l[q])[h4];   // LDS broadcast
                            float r0 = __builtin_amdgcn_rcpf(__builtin_amdgcn_exp2f(qh.x + k0) + 1.0f);
                            float r1 = __builtin_amdgcn_rcpf(__builtin_amdgcn_exp2f(qh.y + k1) + 1.0f);
                            float r2 = __builtin_amdgcn_rcpf(__builtin_amdgcn_exp2f(qh.z + k2) + 1.0f);
                            float r3 = __builtin_amdgcn_rcpf(__builtin_amdgcn_exp2f(qh.w + k3) + 1.0f);
                            s[q] = fmaf(w4.x, r0, s[q]);
                            s[q] = fmaf(w4.y, r1, s[q]);
                            s[q] = fmaf(w4.z, r2, s[q]);
                            s[q] = fmaf(w4.w, r3, s[q]);
                        }
                    }
                }
#pragma unroll
                for (int q = 0; q < QT; ++q) e[q] = __builtin_amdgcn_exp2f(s[q] * L2E);
            } else {
#pragma unroll
                for (int q = 0; q < QT; ++q) e[q] = 0.f;
            }
            *(float4*)&buf[kl * 8]     = make_float4(e[0], e[1], e[2], e[3]);
            *(float4*)&buf[kl * 8 + 4] = make_float4(e[4], e[5], e[6], e[7]);
#pragma unroll
            for (int q = 0; q < QT; ++q) {
                float s = wred_sum(e[q]);
                if ((t & 63) == 0) red_l[q][wid] = s;
            }
        } else {
#pragma unroll
            for (int q = 0; q < QT; ++q) {
                float s = wred_sum(0.f);
                if ((t & 63) == 0) red_l[q][wid] = s;
            }
        }
    }
    __syncthreads();

    // ---- phase 2: PV, waves split k (row kl handled by wave kl%8) ----
    float4 acc[QT];
#pragma unroll
    for (int q = 0; q < QT; ++q) acc[q] = make_float4(0.f, 0.f, 0.f, 0.f);

    const float* Vb = values + ((size_t)b * NK + kstart) * ND;
#pragma unroll 2
    for (int kl = wid; kl < range8; kl += 8) {
        float4 pA = *(const float4*)&buf[kl * 8];       // wave-uniform broadcast
        float4 pB = *(const float4*)&buf[kl * 8 + 4];
        float4 v = *(const float4*)(Vb + (size_t)kl * ND + dl);  // coalesced 1KB
        acc[0].x = fmaf(pA.x, v.x, acc[0].x); acc[0].y = fmaf(pA.x, v.y, acc[0].y);
        acc[0].z = fmaf(pA.x, v.z, acc[0].z); acc[0].w = fmaf(pA.x, v.w, acc[0].w);
        acc[1].x = fmaf(pA.y, v.x, acc[1].x); acc[1].y = fmaf(pA.y, v.y, acc[1].y);
        acc[1].z = fmaf(pA.y, v.z, acc[1].z); acc[1].w = fmaf(pA.y, v.w, acc[1].w);
        acc[2].x = fmaf(pA.z, v.x, acc[2].x); acc[2].y = fmaf(pA.z, v.y, acc[2].y);
        acc[2].z = fmaf(pA.z, v.z, acc[2].z); acc[2].w = fmaf(pA.z, v.w, acc[2].w);
        acc[3].x = fmaf(pA.w, v.x, acc[3].x); acc[3].y = fmaf(pA.w, v.y, acc[3].y);
        acc[3].z = fmaf(pA.w, v.z, acc[3].z); acc[3].w = fmaf(pA.w, v.w, acc[3].w);
        acc[4].x = fmaf(pB.x, v.x, acc[4].x); acc[4].y = fmaf(pB.x, v.y, acc[4].y);
        acc[4].z = fmaf(pB.x, v.z, acc[4].z); acc[4].w = fmaf(pB.x, v.w, acc[4].w);
        acc[5].x = fmaf(pB.y, v.x, acc[5].x); acc[5].y = fmaf(pB.y, v.y, acc[5].y);
        acc[5].z = fmaf(pB.y, v.z, acc[5].z); acc[5].w = fmaf(pB.y, v.w, acc[5].w);
        acc[6].x = fmaf(pB.z, v.x, acc[6].x); acc[6].y = fmaf(pB.z, v.y, acc[6].y);
        acc[6].z = fmaf(pB.z, v.z, acc[6].z); acc[6].w = fmaf(pB.z, v.w, acc[6].w);
        acc[7].x = fmaf(pB.w, v.x, acc[7].x); acc[7].y = fmaf(pB.w, v.y, acc[7].y);
        acc[7].z = fmaf(pB.w, v.z, acc[7].z); acc[7].w = fmaf(pB.w, v.w, acc[7].w);
    }
    __syncthreads();                          // p-values dead -> reuse buf as scratch

    // ---- phase 3: tree-reduce partials across waves (8 -> 4 -> 2 -> 1) ----
    if (wid >= 4) {
        float* s = buf + (size_t)(wid - 4) * 2048;
#pragma unroll
        for (int q = 0; q < QT; ++q) *(float4*)(s + q * 256 + dl) = acc[q];
    }
    __syncthreads();
    if (wid < 4) {
        const float* s = buf + (size_t)wid * 2048;
#pragma unroll
        for (int q = 0; q < QT; ++q) {
            float4 r = *(const float4*)(s + q * 256 + dl);
            acc[q].x += r.x; acc[q].y += r.y; acc[q].z += r.z; acc[q].w += r.w;
        }
    }
    __syncthreads();
    if (wid >= 2 && wid < 4) {
        float* s = buf + (size_t)(wid - 2) * 2048;
#pragma unroll
        for (int q = 0; q < QT; ++q) *(float4*)(s + q * 256 + dl) = acc[q];
    }
    __syncthreads();
    if (wid < 2) {
        const float* s = buf + (size_t)wid * 2048;
#pragma unroll
        for (int q = 0; q < QT; ++q) {
            float4 r = *(const float4*)(s + q * 256 + dl);
            acc[q].x += r.x; acc[q].y += r.y; acc[q].z += r.z; acc[q].w += r.w;
        }
    }
    __syncthreads();
    if (wid == 1) {
#pragma unroll
        for (int q = 0; q < QT; ++q) *(float4*)(buf + q * 256 + dl) = acc[q];
    }
    __syncthreads();
    if (wid == 0) {
#pragma unroll
        for (int q = 0; q < QT; ++q) {
            float4 r = *(const float4*)(buf + q * 256 + dl);
            acc[q].x += r.x; acc[q].y += r.y; acc[q].z += r.z; acc[q].w += r.w;
            const size_t row4 = ((size_t)(b * NQ + q0 + q) * KSPLIT + sp);
            *(float4*)(po + row4 * ND + dl) = acc[q];
        }
        if (t < QT) {
            float l = 0.f;
#pragma unroll
            for (int i = 0; i < 8; ++i) l += red_l[t][i];
            pml[((size_t)(b * NQ + q0 + t) * KSPLIT + sp)] = l;
        }
    }
}

// ---------- kernel C: combine the four splits ----------
__global__ __launch_bounds__(256) void combine_kernel(
    const float* __restrict__ po, const float* __restrict__ pml,
    float* __restrict__ out)
{
    const int t = threadIdx.x;
    const int row = blockIdx.x * 4 + (t >> 6);
    const int dl = (t & 63) * 4;
    float l = 0.f;
#pragma unroll
    for (int s = 0; s < KSPLIT; ++s) l += pml[row * KSPLIT + s];
    float4 o = make_float4(0.f, 0.f, 0.f, 0.f);
#pragma unroll
    for (int s = 0; s < KSPLIT; ++s) {
        float4 p = *(const float4*)(po + ((size_t)row * KSPLIT + s) * ND + dl);
        o.x += p.x; o.y += p.y; o.z += p.z; o.w += p.w;
    }
    const float inv = 1.0f / l;
    o.x *= inv; o.y *= inv; o.z *= inv; o.w *= inv;
    *(float4*)(out + (size_t)row * ND + dl) = o;
}

extern "C" void kernel_launch(void* const* d_in, const int* in_sizes, int n_in,
                              void* d_out, int out_size, void* d_ws, size_t ws_size,
                              hipStream_t stream) {
    const float* queries   = (const float*)d_in[0];
    const float* keys      = (const float*)d_in[1];
    const float* values    = (const float*)d_in[2];
    const int* valid_lens  = (const int*)d_in[3];
    const float* Wq        = (const float*)d_in[4];
    const float* Wk        = (const float*)d_in[5];
    const float* wv        = (const float*)d_in[6];
    float* out = (float*)d_out;

    float* qp  = (float*)d_ws;                          // NB*NQ*NH      (0.5 MB)
    float* kpT = qp + (size_t)NB * NQ * NH;             // NB*NH*NK      (2 MB)
    float* po  = kpT + (size_t)NB * NH * NK;            // NB*NQ*4*ND    (8 MB)
    float* pml = po + (size_t)NB * NQ * KSPLIT * ND;    // NB*NQ*4

    proj_kernel<<<(NB * NQ + NB * NK) / 16, 256, 0, stream>>>(queries, keys, Wq, Wk, qp, kpT);
    attn_part<<<NB * (NQ / QT) * KSPLIT, 512, 0, stream>>>(values, valid_lens, wv, qp, kpT, po, pml);
    combine_kernel<<<NB * NQ / 4, 256, 0, stream>>>(po, pml, out);
}